// Round 3
// baseline (115.575 us; speedup 1.0000x reference)
//
#include <hip/hip_runtime.h>
#include <stdint.h>

// Problem constants: B=2, S=2048, D=1024, H=16, DH=64; M = B*S = 4096.

typedef __attribute__((ext_vector_type(8))) short s16x8;   // 8 bf16 (MFMA A/B frag)
typedef __attribute__((ext_vector_type(4))) float fx4;     // MFMA C/D frag
typedef __attribute__((ext_vector_type(4))) unsigned int ux4;
typedef __attribute__((ext_vector_type(2))) unsigned int ux2;

__device__ __forceinline__ unsigned short f2bf(float x) {
  unsigned u = __builtin_bit_cast(unsigned, x);
  u += 0x7fffu + ((u >> 16) & 1u);          // RNE
  return (unsigned short)(u >> 16);
}
__device__ __forceinline__ float bf2f(unsigned short h) {
  return __builtin_bit_cast(float, (unsigned)h << 16);
}

// async global->LDS, 16B per lane; LDS dest = wave-uniform base + lane*16
__device__ __forceinline__ void gload_lds16(const void* g, void* l) {
  __builtin_amdgcn_global_load_lds(
      (const __attribute__((address_space(1))) unsigned int*)g,
      (__attribute__((address_space(3))) unsigned int*)l, 16, 0, 0);
}

// ---------------- conversion: f32 -> bf16 ----------------
__global__ void k_conv_bf16(const float* __restrict__ X,
                            unsigned short* __restrict__ Y, int n4) {
  int stride = gridDim.x * blockDim.x;
  for (int i = blockIdx.x * blockDim.x + threadIdx.x; i < n4; i += stride) {
    fx4 v = *(const fx4*)(X + (size_t)i * 4);
    ux2 o;
    o[0] = (unsigned)f2bf(v[0]) | ((unsigned)f2bf(v[1]) << 16);
    o[1] = (unsigned)f2bf(v[2]) | ((unsigned)f2bf(v[3]) << 16);
    *(ux2*)(Y + (size_t)i * 4) = o;
  }
}

// ---------------- transpose + convert: W[k][n] f32 -> Wt[n][k] bf16 ----------------
__global__ void k_transpose_w(const float* __restrict__ W0, const float* __restrict__ W1,
                              const float* __restrict__ W2, const float* __restrict__ W3,
                              unsigned short* __restrict__ T0, unsigned short* __restrict__ T1,
                              unsigned short* __restrict__ T2, unsigned short* __restrict__ T3) {
  const float* W = blockIdx.z == 0 ? W0 : blockIdx.z == 1 ? W1 : blockIdx.z == 2 ? W2 : W3;
  unsigned short* T = blockIdx.z == 0 ? T0 : blockIdx.z == 1 ? T1 : blockIdx.z == 2 ? T2 : T3;
  __shared__ float t[32][33];
  int bx = blockIdx.x * 32, by = blockIdx.y * 32;
  int tx = threadIdx.x, ty = threadIdx.y;
#pragma unroll
  for (int i = 0; i < 32; i += 8)
    t[ty + i][tx] = W[(size_t)(by + ty + i) * 1024 + bx + tx];
  __syncthreads();
#pragma unroll
  for (int i = 0; i < 32; i += 8)
    T[(size_t)(bx + ty + i) * 1024 + by + tx] = f2bf(t[tx][ty + i]);
}

// ---------------- GEMM: C[M x Ntot] = A[M x 1024] * Wt ----
// tile 128x128, BK=64, 256 thr (4 waves 2x2 of 64x64), mfma 16x16x32 bf16.
// MODE 1: f32 C store. MODE 2: fused RMSNorm-over-64 + split to qn/kn/vb
// [32][2048][64] layout (q pre-scaled by 0.125*log2e).
template <int MODE>
__global__ __launch_bounds__(256, 2)
void k_gemm_bt(const unsigned short* __restrict__ A,
               const unsigned short* __restrict__ W0,
               const unsigned short* __restrict__ W1,
               const unsigned short* __restrict__ W2,
               void* __restrict__ Cptr, int ldc,
               unsigned short* __restrict__ qn, unsigned short* __restrict__ kn,
               unsigned short* __restrict__ vb) {
  __shared__ unsigned short As[128 * 64];
  __shared__ unsigned short Bs[128 * 64];
  const int tid = threadIdx.x;
  const int w = tid >> 6, l = tid & 63;
  const int lr = l & 15, lg = l >> 4;
  const int wm = w >> 1, wn = w & 1;
  const int m0 = blockIdx.x * 128;
  const int nt = blockIdx.y;
  const unsigned short* Bt = (nt < 8) ? W0 : (nt < 16) ? W1 : W2;
  const int n0 = (nt & 7) * 128;

  fx4 acc[4][4] = {};

  const int srow = w * 8 + (l >> 3);              // row within a 32-row issue block
  const int skb  = ((l & 7) ^ (l >> 3)) * 8;      // pre-swizzled 16B slot (elements)
  const unsigned short* aB = A  + (size_t)(m0 + srow) * 1024 + skb;
  const unsigned short* bB = Bt + (size_t)(n0 + srow) * 1024 + skb;
  unsigned short* aD = &As[w * 512];
  unsigned short* bD = &Bs[w * 512];
  const int rdswz = (l & 7) << 4;

  for (int kt = 0; kt < 1024; kt += 64) {
    __syncthreads();
#pragma unroll
    for (int j = 0; j < 4; ++j) {
      gload_lds16(aB + j * 32768 + kt, aD + j * 2048);
      gload_lds16(bB + j * 32768 + kt, bD + j * 2048);
    }
    __syncthreads();
#pragma unroll
    for (int ks = 0; ks < 2; ++ks) {
      const int kb = (ks * 64 + lg * 16) ^ rdswz;
      s16x8 af[4], bf[4];
#pragma unroll
      for (int mf = 0; mf < 4; ++mf)
        af[mf] = *(const s16x8*)((const char*)As + (wm * 64 + mf * 16 + lr) * 128 + kb);
#pragma unroll
      for (int nf = 0; nf < 4; ++nf)
        bf[nf] = *(const s16x8*)((const char*)Bs + (wn * 64 + nf * 16 + lr) * 128 + kb);
#pragma unroll
      for (int mf = 0; mf < 4; ++mf)
#pragma unroll
        for (int nf = 0; nf < 4; ++nf)
          acc[mf][nf] = __builtin_amdgcn_mfma_f32_16x16x32_bf16(af[mf], bf[nf], acc[mf][nf], 0, 0, 0);
    }
  }

  // C/D layout: row = (l>>4)*4 + reg, col = l&15
  if (MODE == 1) {
    const int gn = nt * 128 + wn * 64;
    const int gm = m0 + wm * 64;
#pragma unroll
    for (int mf = 0; mf < 4; ++mf)
#pragma unroll
      for (int r = 0; r < 4; ++r) {
        int row = gm + mf * 16 + lg * 4 + r;
        float* C = (float*)Cptr + (size_t)row * ldc + gn;
#pragma unroll
        for (int nf = 0; nf < 4; ++nf) C[nf * 16 + lr] = acc[mf][nf][r];
      }
  } else {
    // MODE 2: RMS over the wave's 64-col head block, write to [32][2048][64]
    const int tz = nt >> 3;                       // 0=q 1=k 2=v
    const int h  = ((nt & 7) << 1) | wn;
    const int gm = m0 + wm * 64;
    unsigned short* base = tz == 0 ? qn : tz == 1 ? kn : vb;
    const float cmul = (tz == 0) ? 0.18033688f : 1.0f;   // 0.125 * log2(e)
#pragma unroll
    for (int mf = 0; mf < 4; ++mf)
#pragma unroll
      for (int r = 0; r < 4; ++r) {
        int m = gm + mf * 16 + lg * 4 + r;
        float ss = 0.f;
#pragma unroll
        for (int nf = 0; nf < 4; ++nf) ss += acc[mf][nf][r] * acc[mf][nf][r];
        ss += __shfl_xor(ss, 1);
        ss += __shfl_xor(ss, 2);
        ss += __shfl_xor(ss, 4);
        ss += __shfl_xor(ss, 8);
        float scale = (tz == 2) ? 1.0f : rsqrtf(ss * (1.0f / 64.0f) + 1e-6f) * cmul;
        int b = m >> 11, s = m & 2047;
        unsigned short* dst = base + ((size_t)(((b << 4) + h) * 2048 + s)) * 64;
#pragma unroll
        for (int nf = 0; nf < 4; ++nf)
          dst[nf * 16 + lr] = f2bf(acc[mf][nf][r] * scale);
      }
  }
}

// ---------------- flash attention (causal), bf16 in/out ----------------
// grid 512: id = traw*32 + bh; tq = traw<8 ? traw : 23-traw (blocks i and i+256
// land on the same CU under round-robin dispatch; their work sums to 34 tiles).
// Block = 128 q rows, 4 waves x 32 rows. KVBLK=64. Fixed softmax max
// (|score| <= 8 by Cauchy-Schwarz after RMS norm): p = exp2(s' - 8*log2e).
// Ps/Vt: 128B rows, XOR swizzle byte^=(row&7)<<4, kv-permuted (kv'=2a+b <-> kv=a+16b)
// consistently in P columns and V rows -> paired u32 P stores, conflict-free.
__global__ __launch_bounds__(256, 2)
void k_attn(const unsigned short* __restrict__ Q,   // [32][2048][64], pre-scaled
            const unsigned short* __restrict__ K,
            const unsigned short* __restrict__ V,
            unsigned short* __restrict__ O) {       // [2][2048][1024]
  __shared__ unsigned short Ks[2][64 * 64];     // [kv][dh] swizzled, 8KB each
  __shared__ unsigned short Vt[2][64 * 64];     // [dh][kv'] swizzled, 8KB each
  __shared__ unsigned short Ps[4][32 * 64];     // per-wave P [row][kv'] swizzled, 4KB

  const int id = blockIdx.x;
  const int bh = id & 31;
  const int traw = id >> 5;                     // 0..15
  const int tq = (traw < 8) ? traw : 23 - traw;
  const int q0 = tq * 128;
  const int tid = threadIdx.x;
  const int w = tid >> 6, l = tid & 63;
  const int lr = l & 15, lg = l >> 4;
  const int b = bh >> 4, h = bh & 15;
  const int qw = q0 + w * 32;

  const unsigned short* Kb = K + (size_t)bh * 2048 * 64;
  const unsigned short* Vb = V + (size_t)bh * 2048 * 64;
  const unsigned short* Qb = Q + ((size_t)bh * 2048 + qw) * 64;

  // Q fragments: rows mf*16+lr, k = ks*32 + lg*8
  s16x8 aq[2][2];
#pragma unroll
  for (int mf = 0; mf < 2; ++mf)
#pragma unroll
    for (int ks = 0; ks < 2; ++ks)
      aq[mf][ks] = *(const s16x8*)(Qb + (mf * 16 + lr) * 64 + ks * 32 + lg * 8);

  fx4 oacc[2][4] = {};
  float lsum[2][4] = {{0.f, 0.f, 0.f, 0.f}, {0.f, 0.f, 0.f, 0.f}};

  const int ksrow = w * 8 + (l >> 3);
  const int kskb = ((l & 7) ^ (l >> 3)) * 8;    // pre-swizzled 16B slot (elements)
  const int vhalf = (tid & 31) >> 4;            // 0/1
  const int va_   = tid & 15;
  const int vdhg  = tid >> 5;                   // 0..7
  const int vr0   = vhalf * 32 + va_;           // V rows vr0 and vr0+16
  const int rdswz = (lr & 7) << 4;
  const float FMAX = 11.5415603f;               // 8 * log2(e)

  const int ntl = 2 * (tq + 1);

  // prologue: stage tile 0 into buffer 0
  ux4 va0, va1;
#pragma unroll
  for (int j = 0; j < 2; ++j)
    gload_lds16(Kb + (size_t)(j * 32 + ksrow) * 64 + kskb, &Ks[0][j * 2048 + w * 512]);
  va0 = *(const ux4*)(Vb + (size_t)vr0 * 64 + vdhg * 8);
  va1 = *(const ux4*)(Vb + (size_t)(vr0 + 16) * 64 + vdhg * 8);
  {
    union { ux4 v; unsigned short u[8]; } a0, a1;
    a0.v = va0; a1.v = va1;
#pragma unroll
    for (int i = 0; i < 8; ++i) {
      int dh = vdhg * 8 + i;
      *(unsigned*)((char*)&Vt[0][0] + dh * 128 + ((vhalf * 64 + va_ * 4) ^ (i << 4))) =
          (unsigned)a0.u[i] | ((unsigned)a1.u[i] << 16);
    }
  }
  __syncthreads();

#pragma unroll 1
  for (int t = 0; t < ntl; ++t) {
    const int cur = t & 1;
    const int kv0 = t * 64;
    const bool pre = (t + 1 < ntl);
    if (pre) {
      const int kvn = kv0 + 64;
#pragma unroll
      for (int j = 0; j < 2; ++j)
        gload_lds16(Kb + (size_t)(kvn + j * 32 + ksrow) * 64 + kskb,
                    &Ks[cur ^ 1][j * 2048 + w * 512]);
      va0 = *(const ux4*)(Vb + (size_t)(kvn + vr0) * 64 + vdhg * 8);
      va1 = *(const ux4*)(Vb + (size_t)(kvn + vr0 + 16) * 64 + vdhg * 8);
    }
    if (kv0 <= qw + 31) {                       // wave has unmasked work here
      // QK^T
      fx4 sc[2][4] = {};
#pragma unroll
      for (int ks = 0; ks < 2; ++ks) {
        const int kb = (ks * 64 + lg * 16) ^ rdswz;
#pragma unroll
        for (int nf = 0; nf < 4; ++nf) {
          s16x8 bk = *(const s16x8*)((const char*)&Ks[cur][0] + (nf * 16 + lr) * 128 + kb);
#pragma unroll
          for (int mf = 0; mf < 2; ++mf)
            sc[mf][nf] = __builtin_amdgcn_mfma_f32_16x16x32_bf16(aq[mf][ks], bk, sc[mf][nf], 0, 0, 0);
        }
      }
      if (kv0 + 63 > qw) {                      // causal boundary for this wave
#pragma unroll
        for (int mf = 0; mf < 2; ++mf)
#pragma unroll
          for (int nf = 0; nf < 4; ++nf)
#pragma unroll
            for (int r = 0; r < 4; ++r) {
              int gq = qw + mf * 16 + lg * 4 + r;
              int gk = kv0 + nf * 16 + lr;
              if (gk > gq) sc[mf][nf][r] = -3.0e38f;
            }
      }
      // softmax, fixed max; P -> LDS as paired u32 (kv' layout), swizzled
      char* pw = (char*)&Ps[w][0];
#pragma unroll
      for (int mf = 0; mf < 2; ++mf)
#pragma unroll
        for (int r = 0; r < 4; ++r) {
          float p0 = __builtin_amdgcn_exp2f(sc[mf][0][r] - FMAX);
          float p1 = __builtin_amdgcn_exp2f(sc[mf][1][r] - FMAX);
          float p2 = __builtin_amdgcn_exp2f(sc[mf][2][r] - FMAX);
          float p3 = __builtin_amdgcn_exp2f(sc[mf][3][r] - FMAX);
          lsum[mf][r] += (p0 + p1) + (p2 + p3);
          int row = mf * 16 + lg * 4 + r;
          char* pb = pw + row * 128;
          int swz = (row & 7) << 4;
          *(unsigned*)(pb + ((4 * lr) ^ swz))      = (unsigned)f2bf(p0) | ((unsigned)f2bf(p1) << 16);
          *(unsigned*)(pb + ((64 + 4 * lr) ^ swz)) = (unsigned)f2bf(p2) | ((unsigned)f2bf(p3) << 16);
        }
      // PV (A = P rows mf*16+lr over kv', B = Vt rows dh over kv')
#pragma unroll
      for (int ks = 0; ks < 2; ++ks) {
        s16x8 pa[2], bv[4];
#pragma unroll
        for (int mf = 0; mf < 2; ++mf) {
          int row = mf * 16 + lr;
          pa[mf] = *(const s16x8*)(pw + row * 128 + ((ks * 64 + lg * 16) ^ ((row & 7) << 4)));
        }
#pragma unroll
        for (int nf = 0; nf < 4; ++nf) {
          int row = nf * 16 + lr;
          bv[nf] = *(const s16x8*)((const char*)&Vt[cur][0] + row * 128 +
                                   ((ks * 64 + lg * 16) ^ ((row & 7) << 4)));
        }
#pragma unroll
        for (int mf = 0; mf < 2; ++mf)
#pragma unroll
          for (int nf = 0; nf < 4; ++nf)
            oacc[mf][nf] = __builtin_amdgcn_mfma_f32_16x16x32_bf16(pa[mf], bv[nf], oacc[mf][nf], 0, 0, 0);
      }
    }
    if (pre) {                                  // late write of next V tile
      union { ux4 v; unsigned short u[8]; } a0, a1;
      a0.v = va0; a1.v = va1;
#pragma unroll
      for (int i = 0; i < 8; ++i) {
        int dh = vdhg * 8 + i;
        *(unsigned*)((char*)&Vt[cur ^ 1][0] + dh * 128 + ((vhalf * 64 + va_ * 4) ^ (i << 4))) =
            (unsigned)a0.u[i] | ((unsigned)a1.u[i] << 16);
      }
    }
    __syncthreads();
  }

  // epilogue: one cross-lane reduce per row-group
#pragma unroll
  for (int mf = 0; mf < 2; ++mf)
#pragma unroll
    for (int r = 0; r < 4; ++r) {
      float s = lsum[mf][r];
      s += __shfl_xor(s, 1);
      s += __shfl_xor(s, 2);
      s += __shfl_xor(s, 4);
      s += __shfl_xor(s, 8);
      float inv = 1.0f / s;
      int gq = qw + mf * 16 + lg * 4 + r;
      unsigned short* orow = O + ((size_t)(b * 2048 + gq)) * 1024 + h * 64;
#pragma unroll
      for (int nf = 0; nf < 4; ++nf)
        orow[nf * 16 + lr] = f2bf(oacc[mf][nf][r] * inv);
    }
}

// ---------------- launch ----------------
extern "C" void kernel_launch(void* const* d_in, const int* in_sizes, int n_in,
                              void* d_out, int out_size, void* d_ws, size_t ws_size,
                              hipStream_t stream) {
  const float* x  = (const float*)d_in[0];
  const float* Wq = (const float*)d_in[1];
  const float* Wk = (const float*)d_in[2];
  const float* Wv = (const float*)d_in[3];
  const float* Wo = (const float*)d_in[4];
  // d_in[5] = causal mask (tril) — implemented analytically.

  char* ws = (char*)d_ws;                                  // needs 48 MB
  unsigned short* xb   = (unsigned short*)(ws);            // 8 MB  [4096][1024]
  unsigned short* WqT  = (unsigned short*)(ws + (8ll  << 20));
  unsigned short* WkT  = (unsigned short*)(ws + (10ll << 20));
  unsigned short* WvT  = (unsigned short*)(ws + (12ll << 20));
  unsigned short* WoT  = (unsigned short*)(ws + (14ll << 20));
  unsigned short* qn   = (unsigned short*)(ws + (16ll << 20)); // 8 MB [32][2048][64]
  unsigned short* kn   = (unsigned short*)(ws + (24ll << 20));
  unsigned short* vb   = (unsigned short*)(ws + (32ll << 20));
  unsigned short* attn = (unsigned short*)(ws + (40ll << 20)); // 8 MB [4096][1024]

  k_conv_bf16<<<1024, 256, 0, stream>>>(x, xb, 4096 * 1024 / 4);
  k_transpose_w<<<dim3(32, 32, 4), dim3(32, 8), 0, stream>>>(Wq, Wk, Wv, Wo, WqT, WkT, WvT, WoT);
  k_gemm_bt<2><<<dim3(32, 24), 256, 0, stream>>>(xb, WqT, WkT, WvT, nullptr, 0, qn, kn, vb);
  k_attn<<<512, 256, 0, stream>>>(qn, kn, vb, attn);
  k_gemm_bt<1><<<dim3(32, 8), 256, 0, stream>>>(attn, WoT, WoT, WoT, d_out, 1024, nullptr, nullptr, nullptr);
}